// Round 7
// baseline (281.296 us; speedup 1.0000x reference)
//
#include <hip/hip_runtime.h>
#include <stdint.h>

// Self-attention, B=4, S=2048, D=1024, fp32 in/out, bf16 MFMA internally.
// R12: algebraic fusion. scores = QK^T/32 = (x M x^T)/32 + q~_i + k~_j + c4
//      with M = Wq^T Wk. Eliminates the K projection (-17.2 GF) and makes
//      proj exactly 1024 GEMM jobs (one resident block-wave, zero tail).
//      - Mt = (Wq^T Wk)^T * (1/32), bf16: 64 reg-staged-transpose MFMA blocks
//        fused into the cast dispatch (read fp32 Wq/Wk directly).
//      - w2 = Wq^T bk /32, w3 = Wk^T bq /32: atomic partials in cast
//        (pre-zeroed by hipMemsetAsync); c4 = bq.bk/32: 1 block.
//      - proj: T = x@Mt^T (512 jobs) + V^T (512) + q~/k~ dot jobs (128).
//      - exp: S = T@x^T + q~_i + k~_j + c4, then exp + row sums.
//      GEMM core/exp/pv structure = R11 (best, 221.2us) unchanged.

typedef float f32x4 __attribute__((ext_vector_type(4)));
typedef short s16x8 __attribute__((ext_vector_type(8)));

__device__ __forceinline__ uint16_t f2bf(float f) {
    uint32_t u = __float_as_uint(f);
    u += 0x7fffu + ((u >> 16) & 1u);   // round-to-nearest-even
    return (uint16_t)(u >> 16);
}

__device__ __forceinline__ float bf2f(short v) {
    return __uint_as_float(((uint32_t)(uint16_t)v) << 16);
}

#define GLOAD16(gp, lp)                                                  \
    __builtin_amdgcn_global_load_lds(                                    \
        (const __attribute__((address_space(1))) uint32_t*)(gp),         \
        (__attribute__((address_space(3))) uint32_t*)(lp), 16, 0, 0)

// bijective XCD-contiguity swizzle; valid because grid is %8==0.
__device__ __forceinline__ int xcd_swz(int b, int nwg) {
    return (b & 7) * (nwg >> 3) + (b >> 3);
}

// ---------------------------------------------------------------------------
// BK=64 swizzle (verified SQ_LDS_BANK_CONFLICT=0): LDS chunk cs (16B units)
// holds global kchunk (cs&7)^((cs>>3)&7) of row cs>>3. Fragment read for
// (row, kc): row*64 + (kc^(row&7))*8. C/D: row=(lane>>4)*4+reg, col=lane&15.
// 2-barrier K-loop, 128x128 tile, 4 waves (2x2 of 64x64), acc[4][4].
// u32 self-advancing byte offsets keep arch-VGPR at 64 (4 blocks/CU).
// ---------------------------------------------------------------------------
__device__ __forceinline__ void gemm_core(
    uint16_t* __restrict__ As, uint16_t* __restrict__ Bs,
    const uint16_t* __restrict__ Ag, const int lda,
    const uint16_t* __restrict__ Bg, const int ldb,
    const int NT, f32x4 (&acc)[4][4])
{
    const int t = threadIdx.x;
    const int wave = t >> 6, lane = t & 63;
    const int wm = (wave >> 1) * 64, wn = (wave & 1) * 64;
    const int lr = lane & 15, hi = lane >> 4, lr7 = lane & 7;

    uint32_t offA[4], offB[4];          // byte offsets into Ag/Bg
#pragma unroll
    for (int p = 0; p < 4; ++p) {
        const int cs = p * 256 + t;
        const int rr = cs >> 3;
        const int kc = ((cs & 7) ^ (rr & 7)) * 8;
        offA[p] = (uint32_t)((rr * lda + kc) * 2);
        offB[p] = (uint32_t)((rr * ldb + kc) * 2);
    }
    const int lws = wave * 512;         // LDS write base (uint16 units)

    for (int it = 0; it < NT; ++it) {
#pragma unroll
        for (int p = 0; p < 4; ++p) {
            GLOAD16((const uint8_t*)Ag + offA[p], As + p * 2048 + lws);
            offA[p] += 128;
        }
#pragma unroll
        for (int p = 0; p < 4; ++p) {
            GLOAD16((const uint8_t*)Bg + offB[p], Bs + p * 2048 + lws);
            offB[p] += 128;
        }
        __syncthreads();
#pragma unroll
        for (int kk = 0; kk < 2; ++kk) {
            const int lka = ((kk * 4 + hi) ^ lr7) * 8;
            s16x8 a[4], b[4];
#pragma unroll
            for (int i = 0; i < 4; ++i)
                a[i] = *(const s16x8*)(As + (wm + i * 16 + lr) * 64 + lka);
#pragma unroll
            for (int j = 0; j < 4; ++j)
                b[j] = *(const s16x8*)(Bs + (wn + j * 16 + lr) * 64 + lka);
#pragma unroll
            for (int i = 0; i < 4; ++i)
#pragma unroll
                for (int j = 0; j < 4; ++j)
                    acc[i][j] = __builtin_amdgcn_mfma_f32_16x16x32_bf16(
                        a[i], b[j], acc[i][j], 0, 0, 0);
        }
        __syncthreads();
    }
}

// Cast + precompute dispatch (9545 blocks):
//  b 0..63:       Mt tiles (first -> start early, finish inside cast window)
//  b 64..8255:    x -> xb (bf16)
//  b 8256..8383:  w2 += bk[e]*Wq[e][:] /32   (8 rows per block, atomics)
//  b 8384..8511:  w3 += bq[e]*Wk[e][:] /32
//  b 8512..9535:  Wv -> wvb
//  b 9536..9543:  zero sums
//  b 9544:        c4 = dot(bq,bk)/32
__global__ void cast_all(const float* __restrict__ x, const float* __restrict__ Wq,
                         const float* __restrict__ Wk, const float* __restrict__ Wv,
                         const float* __restrict__ bq, const float* __restrict__ bk,
                         uint16_t* __restrict__ xb, uint16_t* __restrict__ wvb,
                         uint16_t* __restrict__ mtb, float* __restrict__ w2,
                         float* __restrict__ w3, float* __restrict__ c4,
                         float* __restrict__ sums)
{
    __shared__ __attribute__((aligned(16))) uint16_t As[128 * 64];
    __shared__ __attribute__((aligned(16))) uint16_t Bs[128 * 64];
    const int b = blockIdx.x;
    const int t = threadIdx.x;

    if (b < 64) {
        // Mt[d'][d] = sum_e Wk[e][d'] * Wq[e][d], scaled 1/32, bf16.
        // A-tile = Wk columns (row0 range), B-tile = Wq columns (col0 range),
        // both reg-staged TRANSPOSED into the standard swizzled LDS layout.
        const int rowblk = b >> 3, colblk = b & 7;
        const int wave = t >> 6, lane = t & 63;
        const int wm = (wave >> 1) * 64, wn = (wave & 1) * 64;
        const int lr = lane & 15, hi = lane >> 4, lr7 = lane & 7;
        const int quad = t & 31, ep0 = t >> 5;
        f32x4 acc[4][4] = {};
        for (int e0 = 0; e0 < 1024; e0 += 64) {
#pragma unroll
            for (int p = 0; p < 4; ++p) {
                const int e = (ep0 + p * 8) * 2;       // local e, even
                const int dq = quad * 4;
                const float* ka = Wk + (long long)(e0 + e) * 1024 + rowblk * 128 + dq;
                const float* qa = Wq + (long long)(e0 + e) * 1024 + colblk * 128 + dq;
                float4 a0 = *(const float4*)ka;
                float4 a1 = *(const float4*)(ka + 1024);
                float4 b0 = *(const float4*)qa;
                float4 b1 = *(const float4*)(qa + 1024);
                const float* a0p = (const float*)&a0;
                const float* a1p = (const float*)&a1;
                const float* b0p = (const float*)&b0;
                const float* b1p = (const float*)&b1;
#pragma unroll
                for (int m = 0; m < 4; ++m) {
                    const int d = dq + m;
                    const int idx = d * 64 + (((e >> 3) ^ (d & 7)) * 8) + (e & 7);
                    *(uint32_t*)(As + idx) =
                        (uint32_t)f2bf(a0p[m]) | ((uint32_t)f2bf(a1p[m]) << 16);
                    *(uint32_t*)(Bs + idx) =
                        (uint32_t)f2bf(b0p[m]) | ((uint32_t)f2bf(b1p[m]) << 16);
                }
            }
            __syncthreads();
#pragma unroll
            for (int kk = 0; kk < 2; ++kk) {
                const int lka = ((kk * 4 + hi) ^ lr7) * 8;
                s16x8 a[4], bb[4];
#pragma unroll
                for (int i = 0; i < 4; ++i)
                    a[i] = *(const s16x8*)(As + (wm + i * 16 + lr) * 64 + lka);
#pragma unroll
                for (int j = 0; j < 4; ++j)
                    bb[j] = *(const s16x8*)(Bs + (wn + j * 16 + lr) * 64 + lka);
#pragma unroll
                for (int i = 0; i < 4; ++i)
#pragma unroll
                    for (int j = 0; j < 4; ++j)
                        acc[i][j] = __builtin_amdgcn_mfma_f32_16x16x32_bf16(
                            a[i], bb[j], acc[i][j], 0, 0, 0);
            }
            __syncthreads();
        }
        const int row0 = rowblk * 128, col0 = colblk * 128;
#pragma unroll
        for (int i = 0; i < 4; ++i)
#pragma unroll
            for (int rr = 0; rr < 4; ++rr) {
                const int row = row0 + wm + i * 16 + hi * 4 + rr;
#pragma unroll
                for (int j = 0; j < 4; ++j) {
                    const int col = col0 + wn + j * 16 + lr;
                    mtb[row * 1024 + col] = f2bf(acc[i][j][rr] * 0.03125f);
                }
            }
        return;
    }
    if (b < 8256) {                       // x cast
        const int i = (b - 64) * 256 + t;
        float4 v = ((const float4*)x)[i];
        ((ushort4*)xb)[i] = make_ushort4(f2bf(v.x), f2bf(v.y), f2bf(v.z), f2bf(v.w));
        return;
    }
    if (b < 8384) {                       // w2 partials (Wq rows, bk)
        const int blk = b - 8256;
        float4 a = make_float4(0.f, 0.f, 0.f, 0.f);
#pragma unroll
        for (int r = 0; r < 8; ++r) {
            const int e = blk * 8 + r;
            const float s = bk[e];
            float4 v = ((const float4*)(Wq + (long long)e * 1024))[t];
            a.x += s * v.x; a.y += s * v.y; a.z += s * v.z; a.w += s * v.w;
        }
        const int d = t * 4;
        atomicAdd(&w2[d + 0], a.x * 0.03125f);
        atomicAdd(&w2[d + 1], a.y * 0.03125f);
        atomicAdd(&w2[d + 2], a.z * 0.03125f);
        atomicAdd(&w2[d + 3], a.w * 0.03125f);
        return;
    }
    if (b < 8512) {                       // w3 partials (Wk rows, bq)
        const int blk = b - 8384;
        float4 a = make_float4(0.f, 0.f, 0.f, 0.f);
#pragma unroll
        for (int r = 0; r < 8; ++r) {
            const int e = blk * 8 + r;
            const float s = bq[e];
            float4 v = ((const float4*)(Wk + (long long)e * 1024))[t];
            a.x += s * v.x; a.y += s * v.y; a.z += s * v.z; a.w += s * v.w;
        }
        const int d = t * 4;
        atomicAdd(&w3[d + 0], a.x * 0.03125f);
        atomicAdd(&w3[d + 1], a.y * 0.03125f);
        atomicAdd(&w3[d + 2], a.z * 0.03125f);
        atomicAdd(&w3[d + 3], a.w * 0.03125f);
        return;
    }
    if (b < 9536) {                       // Wv cast
        const int i = (b - 8512) * 256 + t;
        float4 v = ((const float4*)Wv)[i];
        ((ushort4*)wvb)[i] = make_ushort4(f2bf(v.x), f2bf(v.y), f2bf(v.z), f2bf(v.w));
        return;
    }
    if (b < 9544) {                       // zero sums
        const int j = (b - 9536) * 256 + t;
        ((float4*)sums)[j] = make_float4(0.f, 0.f, 0.f, 0.f);
        return;
    }
    {                                     // c4 = dot(bq,bk)/32
        float4 a = ((const float4*)bq)[t];
        float4 bb = ((const float4*)bk)[t];
        float s = a.x * bb.x + a.y * bb.y + a.z * bb.z + a.w * bb.w;
        s += __shfl_xor(s, 1);  s += __shfl_xor(s, 2);  s += __shfl_xor(s, 4);
        s += __shfl_xor(s, 8);  s += __shfl_xor(s, 16); s += __shfl_xor(s, 32);
        float* red = (float*)As;
        if ((t & 63) == 0) red[t >> 6] = s;
        __syncthreads();
        if (t == 0) *c4 = (red[0] + red[1] + red[2] + red[3]) * 0.03125f;
    }
}

// Proj dispatch, 1152 blocks (XCD-swizzled):
//   id 0..511:    T = xb @ Mt^T  (rowblk=id>>3 of 64, colblk=id&7)
//   id 512..1023: V^T = Wv @ xb^T + bv (vid=id-512: rb=vid&7, cb=vid>>3)
//   id 1024..1151: q~/k~ dot jobs (64+64): out[row] = dot(xb_row, w2|w3)
__global__ __launch_bounds__(256, 4) void proj_all(
    const uint16_t* __restrict__ xb, const uint16_t* __restrict__ mtb,
    const uint16_t* __restrict__ wvb, const float* __restrict__ bv,
    const float* __restrict__ w2, const float* __restrict__ w3,
    uint16_t* __restrict__ tb, uint16_t* __restrict__ vtb,
    float* __restrict__ qv, float* __restrict__ kv)
{
    __shared__ __attribute__((aligned(16))) uint16_t As[128 * 64];
    __shared__ __attribute__((aligned(16))) uint16_t Bs[128 * 64];

    const int id = xcd_swz(blockIdx.x, 1152);
    const int t = threadIdx.x;
    const int wave = t >> 6, lane = t & 63;

    if (id >= 1024) {                     // dot jobs
        const int dj = id - 1024;
        const float* wvec = (dj < 64) ? w2 : w3;
        float* outv = (dj < 64) ? qv : kv;
        const int base = (dj & 63) * 128 + wave * 32;
        float wreg[16];
#pragma unroll
        for (int m = 0; m < 16; ++m) wreg[m] = wvec[lane * 16 + m];
        for (int rr = 0; rr < 32; ++rr) {
            const int row = base + rr;
            const s16x8* xp = (const s16x8*)(xb + (long long)row * 1024 + lane * 16);
            const s16x8 v0 = xp[0], v1 = xp[1];
            float s = 0.f;
#pragma unroll
            for (int m = 0; m < 8; ++m) {
                s += bf2f(v0[m]) * wreg[m];
                s += bf2f(v1[m]) * wreg[8 + m];
            }
            s += __shfl_xor(s, 1);  s += __shfl_xor(s, 2);  s += __shfl_xor(s, 4);
            s += __shfl_xor(s, 8);  s += __shfl_xor(s, 16); s += __shfl_xor(s, 32);
            if (lane == 0) outv[row] = s;
        }
        return;
    }

    const int wm = (wave >> 1) * 64, wn = (wave & 1) * 64;
    const int lr = lane & 15, hi = lane >> 4;
    f32x4 acc[4][4] = {};

    if (id < 512) {                       // T jobs
        const long long row0 = (long long)(id >> 3) * 128;
        const long long col0 = (long long)(id & 7) * 128;
        gemm_core(As, Bs, xb + row0 * 1024, 1024, mtb + col0 * 1024, 1024, 16, acc);
#pragma unroll
        for (int i = 0; i < 4; ++i)
#pragma unroll
            for (int rr = 0; rr < 4; ++rr) {
                const long long row = row0 + wm + i * 16 + hi * 4 + rr;
#pragma unroll
                for (int j = 0; j < 4; ++j) {
                    const long long col = col0 + wn + j * 16 + lr;
                    tb[row * 1024 + col] = f2bf(acc[i][j][rr]);
                }
            }
    } else {                              // V^T jobs
        const int vid = id - 512;
        const long long row0 = (long long)(vid & 7) * 128;    // Vt row
        const long long col0 = (long long)(vid >> 3) * 128;   // token col
        gemm_core(As, Bs, wvb + row0 * 1024, 1024, xb + col0 * 1024, 1024, 16, acc);
#pragma unroll
        for (int i = 0; i < 4; ++i)
#pragma unroll
            for (int rr = 0; rr < 4; ++rr) {
                const long long row = row0 + wm + i * 16 + hi * 4 + rr;
                const float bb = bv[row];
#pragma unroll
                for (int j = 0; j < 4; ++j) {
                    const long long col = col0 + wn + j * 16 + lr;
                    vtb[row * 8192 + col] = f2bf(acc[i][j][rr] + bb);
                }
            }
    }
}

// P = exp(T@x^T + q~_i + k~_j + c4) + fused row-sum atomics. 1024 blocks.
__global__ __launch_bounds__(256, 4) void gemm_exp(
    const uint16_t* __restrict__ Tm, const uint16_t* __restrict__ X,
    uint16_t* __restrict__ P, float* __restrict__ sums,
    const float* __restrict__ qv, const float* __restrict__ kv,
    const float* __restrict__ c4p)
{
    __shared__ __attribute__((aligned(16))) uint16_t As[128 * 64];
    __shared__ __attribute__((aligned(16))) uint16_t Bs[128 * 64];

    const int id = xcd_swz(blockIdx.x, 1024);
    const int z = id >> 8;
    const int rem = id & 255;
    const long long row0 = (long long)(rem & 15) * 128;
    const long long col0 = (long long)(rem >> 4) * 128;

    const uint16_t* Ab = Tm + (long long)z * 2048 * 1024 + row0 * 1024;
    const uint16_t* Bb = X  + (long long)z * 2048 * 1024 + col0 * 1024;
    uint16_t* Cb = P + (long long)z * 2048 * 2048;
    float* ax = sums + (long long)z * 2048;

    f32x4 acc[4][4] = {};
    gemm_core(As, Bs, Ab, 1024, Bb, 1024, 16, acc);

    const int t = threadIdx.x;
    const int wave = t >> 6, lane = t & 63;
    const int wm = (wave >> 1) * 64, wn = (wave & 1) * 64;
    const int lr = lane & 15, hi = lane >> 4;

    const float c4v = *c4p;
    const float* qvz = qv + z * 2048;
    const float* kvz = kv + z * 2048;
    float kc[4];
#pragma unroll
    for (int j = 0; j < 4; ++j)
        kc[j] = kvz[col0 + wn + j * 16 + lr] + c4v;

#pragma unroll
    for (int i = 0; i < 4; ++i)
#pragma unroll
        for (int rr = 0; rr < 4; ++rr) {
            const long long row = row0 + wm + i * 16 + hi * 4 + rr;
            const float qr = qvz[row];
            float s = 0.f;
#pragma unroll
            for (int j = 0; j < 4; ++j) {
                const long long col = col0 + wn + j * 16 + lr;
                const float v = __expf(acc[i][j][rr] + qr + kc[j]);
                Cb[row * 2048 + col] = f2bf(v);
                s += v;
            }
            s += __shfl_xor(s, 1);
            s += __shfl_xor(s, 2);
            s += __shfl_xor(s, 4);
            s += __shfl_xor(s, 8);
            if (lr == 0) atomicAdd(&ax[row], s);
        }
}

// out = (P @ V) * rcp(sums[row]). 512 blocks, 128x128 tiles, NT=32. (R11)
__global__ __launch_bounds__(256, 4) void gemm_pv(
    const uint16_t* __restrict__ P, const uint16_t* __restrict__ Vt,
    float* __restrict__ Out, const float* __restrict__ sums)
{
    __shared__ __attribute__((aligned(16))) uint16_t As[128 * 64];
    __shared__ __attribute__((aligned(16))) uint16_t Bs[128 * 64];

    const int id = xcd_swz(blockIdx.x, 512);
    const int z = id >> 7;
    const int rem = id & 127;
    const long long row0 = (long long)(rem & 15) * 128;   // token row
    const long long col0 = (long long)(rem >> 4) * 128;   // D col

    const uint16_t* Ab = P + (long long)z * 2048 * 2048 + row0 * 2048;
    const uint16_t* Bb = Vt + col0 * 8192 + (long long)z * 2048;
    float* Cb = Out + (long long)z * 2048 * 1024;
    const float* ax = sums + (long long)z * 2048;

    f32x4 acc[4][4] = {};
    gemm_core(As, Bs, Ab, 2048, Bb, 8192, 32, acc);

    const int t = threadIdx.x;
    const int wave = t >> 6, lane = t & 63;
    const int wm = (wave >> 1) * 64, wn = (wave & 1) * 64;
    const int lr = lane & 15, hi = lane >> 4;
#pragma unroll
    for (int i = 0; i < 4; ++i)
#pragma unroll
        for (int rr = 0; rr < 4; ++rr) {
            const long long row = row0 + wm + i * 16 + hi * 4 + rr;
            const float linv = __builtin_amdgcn_rcpf(ax[row]);
#pragma unroll
            for (int j = 0; j < 4; ++j) {
                const long long col = col0 + wn + j * 16 + lr;
                Cb[row * 1024 + col] = acc[i][j][rr] * linv;
            }
        }
}

extern "C" void kernel_launch(void* const* d_in, const int* in_sizes, int n_in,
                              void* d_out, int out_size, void* d_ws, size_t ws_size,
                              hipStream_t stream) {
    const float* x  = (const float*)d_in[0];
    const float* Wq = (const float*)d_in[1];
    const float* bq = (const float*)d_in[2];
    const float* Wk = (const float*)d_in[3];
    const float* bk = (const float*)d_in[4];
    const float* Wv = (const float*)d_in[5];
    const float* bv = (const float*)d_in[6];

    // workspace carve (~86 MiB)
    uint8_t* w = (uint8_t*)d_ws;
    uint16_t* xb  = (uint16_t*)w; w += (size_t)8192 * 1024 * 2;      // 16 MiB
    uint16_t* mtb = (uint16_t*)w; w += (size_t)1024 * 1024 * 2;      //  2 MiB
    uint8_t*  aux = w;            w += (size_t)2 * 1024 * 1024;      //  2 MiB
    uint16_t* wvb = (uint16_t*)w; w += (size_t)1024 * 1024 * 2;      //  2 MiB
    uint16_t* tb  = (uint16_t*)w; w += (size_t)8192 * 1024 * 2;      // 16 MiB
    uint16_t* vtb = (uint16_t*)w; w += (size_t)8192 * 1024 * 2;      // 16 MiB
    uint16_t* pb  = (uint16_t*)w; w += (size_t)4 * 2048 * 2048 * 2;  // 32 MiB
    float*    sums = (float*)w;   w += (size_t)8192 * 4;

    float* w2 = (float*)(aux);                 // 4 KiB
    float* w3 = (float*)(aux + 4096);          // 4 KiB
    float* c4 = (float*)(aux + 8192);          // 4 B
    float* qv = (float*)(aux + 16384);         // 32 KiB
    float* kv = (float*)(aux + 16384 + 32768); // 32 KiB

    // zero the atomic targets (w2, w3, c4) -- capture-legal async memset
    hipMemsetAsync(aux, 0, 8192 + 256, stream);

    // casts + Mt + w2/w3/c4 + zero sums (1 dispatch)
    cast_all<<<dim3(9545), dim3(256), 0, stream>>>(x, Wq, Wk, Wv, bq, bk,
                                                   xb, wvb, mtb, w2, w3, c4, sums);
    // T (= x@Mt^T), V^T, q~/k~: 1152 blocks
    proj_all<<<dim3(1152), dim3(256), 0, stream>>>(xb, mtb, wvb, bv, w2, w3,
                                                   tb, vtb, qv, kv);
    // P = exp(T@x^T + rank-1 terms) + fused row sums: 1024 blocks
    gemm_exp<<<dim3(1024), dim3(256), 0, stream>>>(tb, xb, pb, sums, qv, kv, c4);
    // out = (P @ V) * rcp(sums): 512 blocks
    gemm_pv<<<dim3(512), dim3(256), 0, stream>>>(pb, vtb, (float*)d_out, sums);
}